// Round 3
// baseline (222.101 us; speedup 1.0000x reference)
//
#include <hip/hip_runtime.h>
#include <hip/hip_bf16.h>

// WindowAttention v3: prep(Wconv) + prep_bm(fragment-layout bias/mask) ->
//   qkv (swizzled LDS, dbuf W chunks) -> attn (vectorized bias+mask) -> proj.
// N=128 tokens, B_=1024 windows, C=192, H=6, hd=32.
// ws: biasF f32 [6][16384] (fragment order) | maskF f32 [64][16384] |
//     wbf bf16[576][192] | pwbf bf16[192][192] |
//     q bf16 [b][h][n][d] (pre-scaled) | k same | v bf16 [b][h][d][n] |
//     (optional) attn-out bf16 [b][n][192]
// Fragment order: tile[L*1024 + tid*4 + e] = value at (row,col) for
//   L = rf*8 + rg*2 + cp, cf = cp*4+e, row = wave*32+rf*16+r4+rg, col = cf*16+lr.

typedef float f32x4 __attribute__((ext_vector_type(4)));
typedef short short8 __attribute__((ext_vector_type(8)));
typedef short short4e __attribute__((ext_vector_type(4)));

#define SCALE 0.17677669529663687f

static __device__ __forceinline__ short f2bf(float f) {
  __hip_bfloat16 h = __float2bfloat16(f);
  return __builtin_bit_cast(short, h);
}
static __device__ __forceinline__ f32x4 mfma16(short8 a, short8 b, f32x4 c) {
  return __builtin_amdgcn_mfma_f32_16x16x32_bf16(a, b, c, 0, 0, 0);
}

// ---------------- prep: convert qkv_w/proj_w to bf16 ----------------
__global__ __launch_bounds__(256) void prep_w(const float* __restrict__ qkvw,
                                              const float* __restrict__ projw,
                                              short* __restrict__ wbf,
                                              short* __restrict__ pwbf) {
  int t = blockIdx.x * 256 + threadIdx.x;  // float4 index 0..36863
  const int NQ = 27648;                    // 576*192/4
  float4 f; short* dst;
  if (t < NQ) { f = ((const float4*)qkvw)[t]; dst = wbf + t * 4; }
  else        { f = ((const float4*)projw)[t - NQ]; dst = pwbf + (t - NQ) * 4; }
  short4e o; o[0] = f2bf(f.x); o[1] = f2bf(f.y); o[2] = f2bf(f.z); o[3] = f2bf(f.w);
  *(short4e*)dst = o;
}

// ---------------- prep_bm: bias/mask tiles in MFMA-fragment layout ----------------
__global__ __launch_bounds__(256) void prep_bm(const int* __restrict__ rel,
                                               const float* __restrict__ table,
                                               const float* __restrict__ mask,
                                               float* __restrict__ biasF,
                                               float* __restrict__ maskF) {
  int blk = blockIdx.x, tid = threadIdx.x;
  int lane = tid & 63, wave = tid >> 6;
  int lr = lane & 15, r4 = (lane >> 4) * 4;
  bool isb = blk < 6;
  int h = blk, w = blk - 6;
  float* dst = isb ? biasF + (size_t)h * 16384 : maskF + (size_t)w * 16384;
#pragma unroll
  for (int L = 0; L < 16; ++L) {
    int rf = L >> 3, rg = (L >> 1) & 3, cp = L & 1;
    int row = wave * 32 + rf * 16 + r4 + rg;
    float4 v;
#pragma unroll
    for (int e = 0; e < 4; ++e) {
      int col = (cp * 4 + e) * 16 + lr;
      float val;
      if (isb) val = table[rel[row * 128 + col] * 6 + h];
      else     val = mask[(size_t)w * 16384 + row * 128 + col];
      ((float*)&v)[e] = val;
    }
    ((float4*)dst)[L * 256 + tid] = v;
  }
}

// ---------------- qkv: x[128][192] @ W^T, W streamed in 32-col bf16 chunks ----------------
__global__ __launch_bounds__(256, 2) void qkv_kernel(const float* __restrict__ x,
                                                     const short* __restrict__ wbf,
                                                     short* __restrict__ qb,
                                                     short* __restrict__ kb,
                                                     short* __restrict__ vb) {
  __shared__ short xt[24576];    // [128][192] bf16, XOR-swizzled (byte ^= (row&7)<<4)
  __shared__ short wt[2][6144];  // [32][192] bf16 double buffer, same swizzle
  const int b = blockIdx.x, tid = threadIdx.x;
  const int wave = tid >> 6, lane = tid & 63;
  const int lr = lane & 15, g = lane >> 4;
  const int g16 = g * 16, r4 = g * 4;
  const int rowbase = wave * 32;
  const int xorkey = (lr & 7) << 4;
  char* xtb = (char*)xt;
  char* wtb = (char*)wt;

  int wsoff[3], wdoff[3];
#pragma unroll
  for (int i = 0; i < 3; ++i) {
    int idx8 = i * 256 + tid;
    int r = idx8 / 24, c = idx8 - r * 24;
    wsoff[i] = idx8 * 8;
    wdoff[i] = r * 384 + ((c * 16) ^ ((r & 7) << 4));
  }
  short8 wreg[3];
#pragma unroll
  for (int i = 0; i < 3; ++i) wreg[i] = *(const short8*)(wbf + wsoff[i]);

  const float4* xr = (const float4*)(x + (size_t)b * 24576);
  for (int s = tid; s < 6144; s += 256) {
    float4 f = xr[s];
    int r = s / 48, c8 = s - r * 48;
    int off = r * 384 + ((c8 * 8) ^ ((r & 7) << 4));
    short4e o; o[0] = f2bf(f.x); o[1] = f2bf(f.y); o[2] = f2bf(f.z); o[3] = f2bf(f.w);
    *(short4e*)(xtb + off) = o;
  }
#pragma unroll
  for (int i = 0; i < 3; ++i) *(short8*)(wtb + wdoff[i]) = wreg[i];
  __syncthreads();

  const int rA0 = (rowbase + lr) * 384, rA1 = rA0 + 16 * 384;
  const int wB0 = lr * 384, wB1 = wB0 + 16 * 384;

  for (int ch = 0; ch < 18; ++ch) {
    if (ch < 17) {
#pragma unroll
      for (int i = 0; i < 3; ++i)
        wreg[i] = *(const short8*)(wbf + (ch + 1) * 6144 + wsoff[i]);
    }
    const char* wbuf = wtb + (ch & 1) * 12288;
    f32x4 acc[2][2];
    acc[0][0] = acc[0][1] = acc[1][0] = acc[1][1] = f32x4{0.f, 0.f, 0.f, 0.f};
    const bool isv = (ch >= 12);
#pragma unroll
    for (int ks = 0; ks < 6; ++ks) {
      int cx = (ks * 64 + g16) ^ xorkey;
      short8 xa0 = *(const short8*)(xtb + rA0 + cx);
      short8 xa1 = *(const short8*)(xtb + rA1 + cx);
      short8 wf0 = *(const short8*)(wbuf + wB0 + cx);
      short8 wf1 = *(const short8*)(wbuf + wB1 + cx);
      if (!isv) {
        acc[0][0] = mfma16(xa0, wf0, acc[0][0]);
        acc[0][1] = mfma16(xa0, wf1, acc[0][1]);
        acc[1][0] = mfma16(xa1, wf0, acc[1][0]);
        acc[1][1] = mfma16(xa1, wf1, acc[1][1]);
      } else {
        acc[0][0] = mfma16(wf0, xa0, acc[0][0]);
        acc[0][1] = mfma16(wf0, xa1, acc[0][1]);
        acc[1][0] = mfma16(wf1, xa0, acc[1][0]);
        acc[1][1] = mfma16(wf1, xa1, acc[1][1]);
      }
    }
    if (!isv) {
      int h = (ch < 6) ? ch : ch - 6;
      short* dst = (ch < 6) ? qb : kb;
      float sc = (ch < 6) ? SCALE : 1.0f;
      size_t base = ((size_t)b * 6 + h) * 4096;
#pragma unroll
      for (int rf = 0; rf < 2; ++rf)
#pragma unroll
        for (int cf = 0; cf < 2; ++cf) {
          int d = cf * 16 + lr;
#pragma unroll
          for (int rg = 0; rg < 4; ++rg) {
            int tok = rowbase + rf * 16 + r4 + rg;
            dst[base + (size_t)tok * 32 + d] = f2bf(acc[rf][cf][rg] * sc);
          }
        }
    } else {
      int h = ch - 12;
      size_t base = ((size_t)b * 6 + h) * 4096;
#pragma unroll
      for (int jf = 0; jf < 2; ++jf)
#pragma unroll
        for (int tf = 0; tf < 2; ++tf) {
          int tok = rowbase + tf * 16 + lr;
#pragma unroll
          for (int rg = 0; rg < 4; ++rg) {
            int d = jf * 16 + r4 + rg;
            vb[base + (size_t)d * 128 + tok] = f2bf(acc[jf][tf][rg]);
          }
        }
    }
    if (ch < 17) {
#pragma unroll
      for (int i = 0; i < 3; ++i)
        *(short8*)(wtb + ((ch + 1) & 1) * 12288 + wdoff[i]) = wreg[i];
      __syncthreads();
    }
  }
}

// ---------------- fused attention per (window, head) ----------------
template <bool BF16OUT>
__global__ __launch_bounds__(256) void attn_kernel(const short* __restrict__ qb,
                                                   const short* __restrict__ kb,
                                                   const short* __restrict__ vb,
                                                   const float* __restrict__ biasF,
                                                   const float* __restrict__ maskF,
                                                   float* __restrict__ aoutf,
                                                   short* __restrict__ aoutb) {
  __shared__ short p_lds[128][136];
  int bh = blockIdx.x;
  int b = bh / 6, h = bh % 6;
  const short* qt = qb + (size_t)bh * 4096;
  const short* kt = kb + (size_t)bh * 4096;
  const short* vt = vb + (size_t)bh * 4096;
  const float4* bF4 = (const float4*)(biasF + (size_t)h * 16384);
  const float4* mF4 = (const float4*)(maskF + (size_t)(b & 63) * 16384);
  int tid = threadIdx.x, wave = tid >> 6, lane = tid & 63;
  int lr = lane & 15, lkb = (lane >> 4) * 8, r4 = (lane >> 4) * 4;
  int rowbase = wave * 32;

  f32x4 s[2][8];
  {
    short8 a0 = *(const short8*)&qt[(rowbase + lr) * 32 + lkb];
    short8 a1 = *(const short8*)&qt[(rowbase + 16 + lr) * 32 + lkb];
#pragma unroll
    for (int cf = 0; cf < 8; ++cf) {
      short8 bb = *(const short8*)&kt[(cf * 16 + lr) * 32 + lkb];
      f32x4 z = {0.f, 0.f, 0.f, 0.f};
      s[0][cf] = mfma16(a0, bb, z);
      s[1][cf] = mfma16(a1, bb, z);
    }
  }
#pragma unroll
  for (int rf = 0; rf < 2; ++rf) {
#pragma unroll
    for (int rg = 0; rg < 4; ++rg) {
      int L = rf * 8 + rg * 2;
      float4 bb0 = bF4[L * 256 + tid];
      float4 bb1 = bF4[(L + 1) * 256 + tid];
      float4 mm0 = mF4[L * 256 + tid];
      float4 mm1 = mF4[(L + 1) * 256 + tid];
      int row = rowbase + rf * 16 + r4 + rg;
      float vals[8];
      vals[0] = s[rf][0][rg] + bb0.x + mm0.x;
      vals[1] = s[rf][1][rg] + bb0.y + mm0.y;
      vals[2] = s[rf][2][rg] + bb0.z + mm0.z;
      vals[3] = s[rf][3][rg] + bb0.w + mm0.w;
      vals[4] = s[rf][4][rg] + bb1.x + mm1.x;
      vals[5] = s[rf][5][rg] + bb1.y + mm1.y;
      vals[6] = s[rf][6][rg] + bb1.z + mm1.z;
      vals[7] = s[rf][7][rg] + bb1.w + mm1.w;
      float mx = -1e30f;
#pragma unroll
      for (int cf = 0; cf < 8; ++cf) mx = fmaxf(mx, vals[cf]);
#pragma unroll
      for (int o = 1; o < 16; o <<= 1) mx = fmaxf(mx, __shfl_xor(mx, o));
      float sum = 0.f;
#pragma unroll
      for (int cf = 0; cf < 8; ++cf) { vals[cf] = __expf(vals[cf] - mx); sum += vals[cf]; }
#pragma unroll
      for (int o = 1; o < 16; o <<= 1) sum += __shfl_xor(sum, o);
      float inv = 1.f / sum;
#pragma unroll
      for (int cf = 0; cf < 8; ++cf) p_lds[row][cf * 16 + lr] = f2bf(vals[cf] * inv);
    }
  }
  __syncthreads();
  f32x4 o[2][2];
#pragma unroll
  for (int i = 0; i < 2; ++i)
#pragma unroll
    for (int j = 0; j < 2; ++j) o[i][j] = f32x4{0.f, 0.f, 0.f, 0.f};
#pragma unroll
  for (int ks = 0; ks < 4; ++ks) {
    short8 pa0 = *(const short8*)&p_lds[rowbase + lr][ks * 32 + lkb];
    short8 pa1 = *(const short8*)&p_lds[rowbase + 16 + lr][ks * 32 + lkb];
    short8 b0 = *(const short8*)&vt[lr * 128 + ks * 32 + lkb];
    short8 b1 = *(const short8*)&vt[(16 + lr) * 128 + ks * 32 + lkb];
    o[0][0] = mfma16(pa0, b0, o[0][0]);
    o[0][1] = mfma16(pa0, b1, o[0][1]);
    o[1][0] = mfma16(pa1, b0, o[1][0]);
    o[1][1] = mfma16(pa1, b1, o[1][1]);
  }
#pragma unroll
  for (int rf = 0; rf < 2; ++rf)
#pragma unroll
    for (int cf = 0; cf < 2; ++cf)
#pragma unroll
      for (int rg = 0; rg < 4; ++rg) {
        int tok = rowbase + rf * 16 + r4 + rg;
        int d = cf * 16 + lr;
        if constexpr (BF16OUT)
          aoutb[((size_t)b * 128 + tok) * 192 + h * 32 + d] = f2bf(o[rf][cf][rg]);
        else
          aoutf[((size_t)b * 128 + tok) * 192 + h * 32 + d] = o[rf][cf][rg];
      }
}

// ---------------- proj: ain[128][192] @ proj_w^T + b ----------------
template <bool BF16IN>
__global__ __launch_bounds__(256, 2) void proj_kernel(const float* __restrict__ ainf,
                                                      const short* __restrict__ ainb,
                                                      const short* __restrict__ pwbf,
                                                      const float* __restrict__ pb,
                                                      float* __restrict__ out) {
  __shared__ short at[24576];
  __shared__ short wt[2][6144];
  const int b = blockIdx.x, tid = threadIdx.x;
  const int wave = tid >> 6, lane = tid & 63;
  const int lr = lane & 15, g = lane >> 4;
  const int g16 = g * 16, r4 = g * 4;
  const int rowbase = wave * 32;
  const int xorkey = (lr & 7) << 4;
  char* atb = (char*)at;
  char* wtb = (char*)wt;

  int wsoff[3], wdoff[3];
#pragma unroll
  for (int i = 0; i < 3; ++i) {
    int idx8 = i * 256 + tid;
    int r = idx8 / 24, c = idx8 - r * 24;
    wsoff[i] = idx8 * 8;
    wdoff[i] = r * 384 + ((c * 16) ^ ((r & 7) << 4));
  }
  short8 wreg[3];
#pragma unroll
  for (int i = 0; i < 3; ++i) wreg[i] = *(const short8*)(pwbf + wsoff[i]);

  if constexpr (BF16IN) {
    const short8* ar = (const short8*)(ainb + (size_t)b * 24576);
#pragma unroll
    for (int i = 0; i < 12; ++i) {
      int idx8 = i * 256 + tid;
      int r = idx8 / 24, c = idx8 - r * 24;
      short8 v = ar[idx8];
      *(short8*)(atb + r * 384 + ((c * 16) ^ ((r & 7) << 4))) = v;
    }
  } else {
    const float4* ar = (const float4*)(ainf + (size_t)b * 24576);
    for (int s = tid; s < 6144; s += 256) {
      float4 f = ar[s];
      int r = s / 48, c8 = s - r * 48;
      int off = r * 384 + ((c8 * 8) ^ ((r & 7) << 4));
      short4e o; o[0] = f2bf(f.x); o[1] = f2bf(f.y); o[2] = f2bf(f.z); o[3] = f2bf(f.w);
      *(short4e*)(atb + off) = o;
    }
  }
#pragma unroll
  for (int i = 0; i < 3; ++i) *(short8*)(wtb + wdoff[i]) = wreg[i];
  __syncthreads();

  const int rA0 = (rowbase + lr) * 384, rA1 = rA0 + 16 * 384;
  const int wB0 = lr * 384, wB1 = wB0 + 16 * 384;

  for (int ch = 0; ch < 6; ++ch) {
    if (ch < 5) {
#pragma unroll
      for (int i = 0; i < 3; ++i)
        wreg[i] = *(const short8*)(pwbf + (ch + 1) * 6144 + wsoff[i]);
    }
    const char* wbuf = wtb + (ch & 1) * 12288;
    f32x4 acc[2][2];
    acc[0][0] = acc[0][1] = acc[1][0] = acc[1][1] = f32x4{0.f, 0.f, 0.f, 0.f};
#pragma unroll
    for (int ks = 0; ks < 6; ++ks) {
      int cx = (ks * 64 + g16) ^ xorkey;
      short8 xa0 = *(const short8*)(atb + rA0 + cx);
      short8 xa1 = *(const short8*)(atb + rA1 + cx);
      short8 wf0 = *(const short8*)(wbuf + wB0 + cx);
      short8 wf1 = *(const short8*)(wbuf + wB1 + cx);
      acc[0][0] = mfma16(xa0, wf0, acc[0][0]);
      acc[0][1] = mfma16(xa0, wf1, acc[0][1]);
      acc[1][0] = mfma16(xa1, wf0, acc[1][0]);
      acc[1][1] = mfma16(xa1, wf1, acc[1][1]);
    }
#pragma unroll
    for (int cf = 0; cf < 2; ++cf) {
      int j = ch * 32 + cf * 16 + lr;
      float bj = pb[j];
#pragma unroll
      for (int rf = 0; rf < 2; ++rf)
#pragma unroll
        for (int rg = 0; rg < 4; ++rg) {
          int tok = rowbase + rf * 16 + r4 + rg;
          out[((size_t)b * 128 + tok) * 192 + j] = acc[rf][cf][rg] + bj;
        }
    }
    if (ch < 5) {
#pragma unroll
      for (int i = 0; i < 3; ++i)
        *(short8*)(wtb + ((ch + 1) & 1) * 12288 + wdoff[i]) = wreg[i];
      __syncthreads();
    }
  }
}

extern "C" void kernel_launch(void* const* d_in, const int* in_sizes, int n_in,
                              void* d_out, int out_size, void* d_ws, size_t ws_size,
                              hipStream_t stream) {
  const float* x      = (const float*)d_in[0];
  const float* mask   = (const float*)d_in[1];
  const float* qkv_w  = (const float*)d_in[2];
  const float* proj_w = (const float*)d_in[3];
  const float* proj_b = (const float*)d_in[4];
  const float* table  = (const float*)d_in[5];
  const int*   rel    = (const int*)d_in[6];
  char* ws = (char*)d_ws;
  size_t o = 0;
  float* biasF = (float*)(ws + o); o += 393216;
  float* maskF = (float*)(ws + o); o += 4194304;
  short* wbf   = (short*)(ws + o); o += 221184;
  short* pwbf  = (short*)(ws + o); o += 73728;
  short* qbp   = (short*)(ws + o); o += 50331648;
  short* kbp   = (short*)(ws + o); o += 50331648;
  short* vbp   = (short*)(ws + o); o += 50331648;
  bool bf16path = (ws_size >= o + 50331648);
  short* aoutb = (short*)(ws + o);
  float* out = (float*)d_out;

  prep_w<<<144, 256, 0, stream>>>(qkv_w, proj_w, wbf, pwbf);
  prep_bm<<<70, 256, 0, stream>>>(rel, table, mask, biasF, maskF);
  qkv_kernel<<<1024, 256, 0, stream>>>(x, wbf, qbp, kbp, vbp);
  if (bf16path) {
    attn_kernel<true><<<6144, 256, 0, stream>>>(qbp, kbp, vbp, biasF, maskF, nullptr, aoutb);
    proj_kernel<true><<<1024, 256, 0, stream>>>(nullptr, aoutb, pwbf, proj_b, out);
  } else {
    attn_kernel<false><<<6144, 256, 0, stream>>>(qbp, kbp, vbp, biasF, maskF, out, nullptr);
    proj_kernel<false><<<1024, 256, 0, stream>>>(out, nullptr, pwbf, proj_b, out);
  }
}

// Round 4
// 199.226 us; speedup vs baseline: 1.1148x; 1.1148x over previous
//
#include <hip/hip_runtime.h>
#include <hip/hip_bf16.h>

// WindowAttention v4: barrier-free attn, skip-max exp2 softmax, deferred norm.
// N=128 tokens, B_=1024 windows, C=192, H=6, hd=32.
// ws: biasF f32 [6][16384] (fragment order, pre-scaled by LOG2E) |
//     maskF f32 [64][16384] (fragment order, pre-scaled by LOG2E) |
//     wbf bf16[576][192] | pwbf bf16[192][192] |
//     q bf16 [b][h][n][d] (pre-scaled by SCALE*LOG2E) | k bf16 [b][h][n][d] |
//     v bf16 [b][h][d][n] | (optional) attn-out bf16 [b][n][192]
// Fragment order: tile[L*1024 + tid*4 + e], L = rf*8+rg*2+cp, col=(cp*4+e)*16+lr,
//   row = wave*32+rf*16+r4+rg.

typedef float f32x4 __attribute__((ext_vector_type(4)));
typedef short short8 __attribute__((ext_vector_type(8)));
typedef short short4e __attribute__((ext_vector_type(4)));

#define SCALE 0.17677669529663687f
#define LOG2E 1.4426950408889634f

static __device__ __forceinline__ short f2bf(float f) {
  __hip_bfloat16 h = __float2bfloat16(f);
  return __builtin_bit_cast(short, h);
}
static __device__ __forceinline__ f32x4 mfma16(short8 a, short8 b, f32x4 c) {
  return __builtin_amdgcn_mfma_f32_16x16x32_bf16(a, b, c, 0, 0, 0);
}

// ---------------- prep: convert qkv_w/proj_w to bf16 ----------------
__global__ __launch_bounds__(256) void prep_w(const float* __restrict__ qkvw,
                                              const float* __restrict__ projw,
                                              short* __restrict__ wbf,
                                              short* __restrict__ pwbf) {
  int t = blockIdx.x * 256 + threadIdx.x;  // float4 index 0..36863
  const int NQ = 27648;                    // 576*192/4
  float4 f; short* dst;
  if (t < NQ) { f = ((const float4*)qkvw)[t]; dst = wbf + t * 4; }
  else        { f = ((const float4*)projw)[t - NQ]; dst = pwbf + (t - NQ) * 4; }
  short4e o; o[0] = f2bf(f.x); o[1] = f2bf(f.y); o[2] = f2bf(f.z); o[3] = f2bf(f.w);
  *(short4e*)dst = o;
}

// ---------------- prep bias tiles (fragment layout, x LOG2E) ----------------
__global__ __launch_bounds__(256) void prep_bias(const int* __restrict__ rel,
                                                 const float* __restrict__ table,
                                                 float* __restrict__ biasF) {
  int blk = blockIdx.x;            // 96 blocks: h*16 + L
  int h = blk >> 4, L = blk & 15;
  int tid = threadIdx.x, lane = tid & 63, wave = tid >> 6;
  int lr = lane & 15, r4 = (lane >> 4) * 4;
  int rf = L >> 3, rg = (L >> 1) & 3, cp = L & 1;
  int row = wave * 32 + rf * 16 + r4 + rg;
  float4 v;
#pragma unroll
  for (int e = 0; e < 4; ++e) {
    int col = (cp * 4 + e) * 16 + lr;
    ((float*)&v)[e] = table[rel[row * 128 + col] * 6 + h] * LOG2E;
  }
  ((float4*)(biasF + (size_t)h * 16384))[L * 256 + tid] = v;
}

// ---------------- prep mask tiles (fragment layout, x LOG2E) ----------------
__global__ __launch_bounds__(256) void prep_mask(const float* __restrict__ mask,
                                                 float* __restrict__ maskF) {
  int blk = blockIdx.x;            // 1024 blocks: w*16 + L
  int w = blk >> 4, L = blk & 15;
  int tid = threadIdx.x, lane = tid & 63, wave = tid >> 6;
  int lr = lane & 15, r4 = (lane >> 4) * 4;
  int rf = L >> 3, rg = (L >> 1) & 3, cp = L & 1;
  int row = wave * 32 + rf * 16 + r4 + rg;
  const float* src = mask + (size_t)w * 16384 + row * 128;
  float4 v;
#pragma unroll
  for (int e = 0; e < 4; ++e) {
    int col = (cp * 4 + e) * 16 + lr;
    ((float*)&v)[e] = src[col] * LOG2E;
  }
  ((float4*)(maskF + (size_t)w * 16384))[L * 256 + tid] = v;
}

// ---------------- qkv: x[128][192] @ W^T, W streamed in 32-col bf16 chunks ----------------
__global__ __launch_bounds__(256, 2) void qkv_kernel(const float* __restrict__ x,
                                                     const short* __restrict__ wbf,
                                                     short* __restrict__ qb,
                                                     short* __restrict__ kb,
                                                     short* __restrict__ vb) {
  __shared__ short xt[24576];    // [128][192] bf16, XOR-swizzled (byte ^= (row&7)<<4)
  __shared__ short wt[2][6144];  // [32][192] bf16 double buffer, same swizzle
  const int b = blockIdx.x, tid = threadIdx.x;
  const int wave = tid >> 6, lane = tid & 63;
  const int lr = lane & 15, g = lane >> 4;
  const int g16 = g * 16, r4 = g * 4;
  const int rowbase = wave * 32;
  const int xorkey = (lr & 7) << 4;
  char* xtb = (char*)xt;
  char* wtb = (char*)wt;

  int wsoff[3], wdoff[3];
#pragma unroll
  for (int i = 0; i < 3; ++i) {
    int idx8 = i * 256 + tid;
    int r = idx8 / 24, c = idx8 - r * 24;
    wsoff[i] = idx8 * 8;
    wdoff[i] = r * 384 + ((c * 16) ^ ((r & 7) << 4));
  }
  short8 wreg[3];
#pragma unroll
  for (int i = 0; i < 3; ++i) wreg[i] = *(const short8*)(wbf + wsoff[i]);

  const float4* xr = (const float4*)(x + (size_t)b * 24576);
  for (int s = tid; s < 6144; s += 256) {
    float4 f = xr[s];
    int r = s / 48, c8 = s - r * 48;
    int off = r * 384 + ((c8 * 8) ^ ((r & 7) << 4));
    short4e o; o[0] = f2bf(f.x); o[1] = f2bf(f.y); o[2] = f2bf(f.z); o[3] = f2bf(f.w);
    *(short4e*)(xtb + off) = o;
  }
#pragma unroll
  for (int i = 0; i < 3; ++i) *(short8*)(wtb + wdoff[i]) = wreg[i];
  __syncthreads();

  const int rA0 = (rowbase + lr) * 384, rA1 = rA0 + 16 * 384;
  const int wB0 = lr * 384, wB1 = wB0 + 16 * 384;

  for (int ch = 0; ch < 18; ++ch) {
    if (ch < 17) {
#pragma unroll
      for (int i = 0; i < 3; ++i)
        wreg[i] = *(const short8*)(wbf + (ch + 1) * 6144 + wsoff[i]);
    }
    const char* wbuf = wtb + (ch & 1) * 12288;
    f32x4 acc[2][2];
    acc[0][0] = acc[0][1] = acc[1][0] = acc[1][1] = f32x4{0.f, 0.f, 0.f, 0.f};
    const bool isv = (ch >= 12);
#pragma unroll
    for (int ks = 0; ks < 6; ++ks) {
      int cx = (ks * 64 + g16) ^ xorkey;
      short8 xa0 = *(const short8*)(xtb + rA0 + cx);
      short8 xa1 = *(const short8*)(xtb + rA1 + cx);
      short8 wf0 = *(const short8*)(wbuf + wB0 + cx);
      short8 wf1 = *(const short8*)(wbuf + wB1 + cx);
      if (!isv) {
        acc[0][0] = mfma16(xa0, wf0, acc[0][0]);
        acc[0][1] = mfma16(xa0, wf1, acc[0][1]);
        acc[1][0] = mfma16(xa1, wf0, acc[1][0]);
        acc[1][1] = mfma16(xa1, wf1, acc[1][1]);
      } else {
        acc[0][0] = mfma16(wf0, xa0, acc[0][0]);
        acc[0][1] = mfma16(wf0, xa1, acc[0][1]);
        acc[1][0] = mfma16(wf1, xa0, acc[1][0]);
        acc[1][1] = mfma16(wf1, xa1, acc[1][1]);
      }
    }
    if (!isv) {
      int h = (ch < 6) ? ch : ch - 6;
      short* dst = (ch < 6) ? qb : kb;
      float sc = (ch < 6) ? (SCALE * LOG2E) : 1.0f;
      size_t base = ((size_t)b * 6 + h) * 4096;
#pragma unroll
      for (int rf = 0; rf < 2; ++rf)
#pragma unroll
        for (int cf = 0; cf < 2; ++cf) {
          int d = cf * 16 + lr;
#pragma unroll
          for (int rg = 0; rg < 4; ++rg) {
            int tok = rowbase + rf * 16 + r4 + rg;
            dst[base + (size_t)tok * 32 + d] = f2bf(acc[rf][cf][rg] * sc);
          }
        }
    } else {
      int h = ch - 12;
      size_t base = ((size_t)b * 6 + h) * 4096;
#pragma unroll
      for (int jf = 0; jf < 2; ++jf)
#pragma unroll
        for (int tf = 0; tf < 2; ++tf) {
          int tok = rowbase + tf * 16 + lr;
#pragma unroll
          for (int rg = 0; rg < 4; ++rg) {
            int d = jf * 16 + r4 + rg;
            vb[base + (size_t)d * 128 + tok] = f2bf(acc[jf][tf][rg]);
          }
        }
    }
    if (ch < 17) {
#pragma unroll
      for (int i = 0; i < 3; ++i)
        *(short8*)(wtb + ((ch + 1) & 1) * 12288 + wdoff[i]) = wreg[i];
      __syncthreads();
    }
  }
}

// ---------------- fused attention per (window, head), barrier-free ----------------
template <bool BF16OUT>
__global__ __launch_bounds__(256, 4) void attn_kernel(const short* __restrict__ qb,
                                                      const short* __restrict__ kb,
                                                      const short* __restrict__ vb,
                                                      const float* __restrict__ biasF,
                                                      const float* __restrict__ maskF,
                                                      float* __restrict__ aoutf,
                                                      short* __restrict__ aoutb) {
  __shared__ short p_lds[16384];  // [128][128] bf16, swizzle byte ^= (row&15)<<4
  char* pbuf = (char*)p_lds;
  const int bh = blockIdx.x, b = bh / 6, h = bh - b * 6;
  const short* qt = qb + (size_t)bh * 4096;
  const short* kt = kb + (size_t)bh * 4096;
  const short* vt = vb + (size_t)bh * 4096;
  const float4* bF4 = (const float4*)(biasF + (size_t)h * 16384);
  const float4* mF4 = (const float4*)(maskF + (size_t)(b & 63) * 16384);
  const int tid = threadIdx.x, wave = tid >> 6, lane = tid & 63;
  const int lr = lane & 15, g = lane >> 4, lkb = g * 8, r4 = g * 4;
  const int rowbase = wave * 32;

  float inv[2][4];
#pragma unroll
  for (int rf = 0; rf < 2; ++rf) {
    // QK^T for this rf: 8 MFMA, S row = q-token, col = k-token
    short8 a0 = *(const short8*)&qt[(rowbase + rf * 16 + lr) * 32 + lkb];
    f32x4 s[8];
    __builtin_amdgcn_s_setprio(1);
#pragma unroll
    for (int cf = 0; cf < 8; ++cf) {
      short8 bb = *(const short8*)&kt[(cf * 16 + lr) * 32 + lkb];
      f32x4 z = {0.f, 0.f, 0.f, 0.f};
      s[cf] = mfma16(a0, bb, z);
    }
    __builtin_amdgcn_s_setprio(0);
#pragma unroll
    for (int rg = 0; rg < 4; ++rg) {
      int L = rf * 8 + rg * 2;
      float4 bb0 = bF4[L * 256 + tid];
      float4 bb1 = bF4[(L + 1) * 256 + tid];
      float4 mm0 = mF4[L * 256 + tid];
      float4 mm1 = mF4[(L + 1) * 256 + tid];
      // skip-max softmax in log2 domain (logits pre-scaled by LOG2E)
      float p0 = exp2f(s[0][rg] + bb0.x + mm0.x);
      float p1 = exp2f(s[1][rg] + bb0.y + mm0.y);
      float p2 = exp2f(s[2][rg] + bb0.z + mm0.z);
      float p3 = exp2f(s[3][rg] + bb0.w + mm0.w);
      float p4 = exp2f(s[4][rg] + bb1.x + mm1.x);
      float p5 = exp2f(s[5][rg] + bb1.y + mm1.y);
      float p6 = exp2f(s[6][rg] + bb1.z + mm1.z);
      float p7 = exp2f(s[7][rg] + bb1.w + mm1.w);
      float sum = ((p0 + p1) + (p2 + p3)) + ((p4 + p5) + (p6 + p7));
#pragma unroll
      for (int o = 1; o < 16; o <<= 1) sum += __shfl_xor(sum, o);
      inv[rf][rg] = 1.0f / sum;
      int row = rowbase + rf * 16 + r4 + rg;
      int base = (row << 8) + (lr << 1);
      int swz = (row & 15) << 4;
      *(short*)(pbuf + ((base + 0 * 32) ^ swz)) = f2bf(p0);
      *(short*)(pbuf + ((base + 1 * 32) ^ swz)) = f2bf(p1);
      *(short*)(pbuf + ((base + 2 * 32) ^ swz)) = f2bf(p2);
      *(short*)(pbuf + ((base + 3 * 32) ^ swz)) = f2bf(p3);
      *(short*)(pbuf + ((base + 4 * 32) ^ swz)) = f2bf(p4);
      *(short*)(pbuf + ((base + 5 * 32) ^ swz)) = f2bf(p5);
      *(short*)(pbuf + ((base + 6 * 32) ^ swz)) = f2bf(p6);
      *(short*)(pbuf + ((base + 7 * 32) ^ swz)) = f2bf(p7);
    }
  }
  // PV: no barrier needed — each wave reads only its own 32 rows.
  const int rsw = lr << 4;  // (row&15)<<4 for row = rowbase+lr (+16): == lr<<4
  f32x4 o[2][2];
  o[0][0] = o[0][1] = o[1][0] = o[1][1] = f32x4{0.f, 0.f, 0.f, 0.f};
#pragma unroll
  for (int ks = 0; ks < 4; ++ks) {
    int ra = ((rowbase + lr) << 8) + (ks << 6) + (g << 4);
    short8 pa0 = *(const short8*)(pbuf + ((ra) ^ rsw));
    short8 pa1 = *(const short8*)(pbuf + ((ra + (16 << 8)) ^ rsw));
    short8 b0 = *(const short8*)&vt[lr * 128 + ks * 32 + lkb];
    short8 b1 = *(const short8*)&vt[(16 + lr) * 128 + ks * 32 + lkb];
    __builtin_amdgcn_s_setprio(1);
    o[0][0] = mfma16(pa0, b0, o[0][0]);
    o[0][1] = mfma16(pa0, b1, o[0][1]);
    o[1][0] = mfma16(pa1, b0, o[1][0]);
    o[1][1] = mfma16(pa1, b1, o[1][1]);
    __builtin_amdgcn_s_setprio(0);
  }
#pragma unroll
  for (int rf = 0; rf < 2; ++rf)
#pragma unroll
    for (int cf = 0; cf < 2; ++cf)
#pragma unroll
      for (int rg = 0; rg < 4; ++rg) {
        int tok = rowbase + rf * 16 + r4 + rg;
        int d = cf * 16 + lr;
        float val = o[rf][cf][rg] * inv[rf][rg];
        if constexpr (BF16OUT)
          aoutb[((size_t)b * 128 + tok) * 192 + h * 32 + d] = f2bf(val);
        else
          aoutf[((size_t)b * 128 + tok) * 192 + h * 32 + d] = val;
      }
}

// ---------------- proj: ain[128][192] @ proj_w^T + b ----------------
template <bool BF16IN>
__global__ __launch_bounds__(256, 2) void proj_kernel(const float* __restrict__ ainf,
                                                      const short* __restrict__ ainb,
                                                      const short* __restrict__ pwbf,
                                                      const float* __restrict__ pb,
                                                      float* __restrict__ out) {
  __shared__ short at[24576];
  __shared__ short wt[2][6144];
  const int b = blockIdx.x, tid = threadIdx.x;
  const int wave = tid >> 6, lane = tid & 63;
  const int lr = lane & 15, g = lane >> 4;
  const int g16 = g * 16, r4 = g * 4;
  const int rowbase = wave * 32;
  const int xorkey = (lr & 7) << 4;
  char* atb = (char*)at;
  char* wtb = (char*)wt;

  int wsoff[3], wdoff[3];
#pragma unroll
  for (int i = 0; i < 3; ++i) {
    int idx8 = i * 256 + tid;
    int r = idx8 / 24, c = idx8 - r * 24;
    wsoff[i] = idx8 * 8;
    wdoff[i] = r * 384 + ((c * 16) ^ ((r & 7) << 4));
  }
  short8 wreg[3];
#pragma unroll
  for (int i = 0; i < 3; ++i) wreg[i] = *(const short8*)(pwbf + wsoff[i]);

  if constexpr (BF16IN) {
    const short8* ar = (const short8*)(ainb + (size_t)b * 24576);
#pragma unroll
    for (int i = 0; i < 12; ++i) {
      int idx8 = i * 256 + tid;
      int r = idx8 / 24, c = idx8 - r * 24;
      short8 v = ar[idx8];
      *(short8*)(atb + r * 384 + ((c * 16) ^ ((r & 7) << 4))) = v;
    }
  } else {
    const float4* ar = (const float4*)(ainf + (size_t)b * 24576);
    for (int s = tid; s < 6144; s += 256) {
      float4 f = ar[s];
      int r = s / 48, c8 = s - r * 48;
      int off = r * 384 + ((c8 * 8) ^ ((r & 7) << 4));
      short4e o; o[0] = f2bf(f.x); o[1] = f2bf(f.y); o[2] = f2bf(f.z); o[3] = f2bf(f.w);
      *(short4e*)(atb + off) = o;
    }
  }
#pragma unroll
  for (int i = 0; i < 3; ++i) *(short8*)(wtb + wdoff[i]) = wreg[i];
  __syncthreads();

  const int rA0 = (rowbase + lr) * 384, rA1 = rA0 + 16 * 384;
  const int wB0 = lr * 384, wB1 = wB0 + 16 * 384;

  for (int ch = 0; ch < 6; ++ch) {
    if (ch < 5) {
#pragma unroll
      for (int i = 0; i < 3; ++i)
        wreg[i] = *(const short8*)(pwbf + (ch + 1) * 6144 + wsoff[i]);
    }
    const char* wbuf = wtb + (ch & 1) * 12288;
    f32x4 acc[2][2];
    acc[0][0] = acc[0][1] = acc[1][0] = acc[1][1] = f32x4{0.f, 0.f, 0.f, 0.f};
#pragma unroll
    for (int ks = 0; ks < 6; ++ks) {
      int cx = (ks * 64 + g16) ^ xorkey;
      short8 xa0 = *(const short8*)(atb + rA0 + cx);
      short8 xa1 = *(const short8*)(atb + rA1 + cx);
      short8 wf0 = *(const short8*)(wbuf + wB0 + cx);
      short8 wf1 = *(const short8*)(wbuf + wB1 + cx);
      acc[0][0] = mfma16(xa0, wf0, acc[0][0]);
      acc[0][1] = mfma16(xa0, wf1, acc[0][1]);
      acc[1][0] = mfma16(xa1, wf0, acc[1][0]);
      acc[1][1] = mfma16(xa1, wf1, acc[1][1]);
    }
#pragma unroll
    for (int cf = 0; cf < 2; ++cf) {
      int j = ch * 32 + cf * 16 + lr;
      float bj = pb[j];
#pragma unroll
      for (int rf = 0; rf < 2; ++rf)
#pragma unroll
        for (int rg = 0; rg < 4; ++rg) {
          int tok = rowbase + rf * 16 + r4 + rg;
          out[((size_t)b * 128 + tok) * 192 + j] = acc[rf][cf][rg] + bj;
        }
    }
    if (ch < 5) {
#pragma unroll
      for (int i = 0; i < 3; ++i)
        *(short8*)(wtb + ((ch + 1) & 1) * 12288 + wdoff[i]) = wreg[i];
      __syncthreads();
    }
  }
}

extern "C" void kernel_launch(void* const* d_in, const int* in_sizes, int n_in,
                              void* d_out, int out_size, void* d_ws, size_t ws_size,
                              hipStream_t stream) {
  const float* x      = (const float*)d_in[0];
  const float* mask   = (const float*)d_in[1];
  const float* qkv_w  = (const float*)d_in[2];
  const float* proj_w = (const float*)d_in[3];
  const float* proj_b = (const float*)d_in[4];
  const float* table  = (const float*)d_in[5];
  const int*   rel    = (const int*)d_in[6];
  char* ws = (char*)d_ws;
  size_t o = 0;
  float* biasF = (float*)(ws + o); o += 393216;
  float* maskF = (float*)(ws + o); o += 4194304;
  short* wbf   = (short*)(ws + o); o += 221184;
  short* pwbf  = (short*)(ws + o); o += 73728;
  short* qbp   = (short*)(ws + o); o += 50331648;
  short* kbp   = (short*)(ws + o); o += 50331648;
  short* vbp   = (short*)(ws + o); o += 50331648;
  bool bf16path = (ws_size >= o + 50331648);
  short* aoutb = (short*)(ws + o);
  float* out = (float*)d_out;

  prep_w<<<144, 256, 0, stream>>>(qkv_w, proj_w, wbf, pwbf);
  prep_bias<<<96, 256, 0, stream>>>(rel, table, biasF);
  prep_mask<<<1024, 256, 0, stream>>>(mask, maskF);
  qkv_kernel<<<1024, 256, 0, stream>>>(x, wbf, qbp, kbp, vbp);
  if (bf16path) {
    attn_kernel<true><<<6144, 256, 0, stream>>>(qbp, kbp, vbp, biasF, maskF, nullptr, aoutb);
    proj_kernel<true><<<1024, 256, 0, stream>>>(nullptr, aoutb, pwbf, proj_b, out);
  } else {
    attn_kernel<false><<<6144, 256, 0, stream>>>(qbp, kbp, vbp, biasF, maskF, out, nullptr);
    proj_kernel<false><<<1024, 256, 0, stream>>>(out, nullptr, pwbf, proj_b, out);
  }
}